// Round 1
// baseline (527.090 us; speedup 1.0000x reference)
//
#include <hip/hip_runtime.h>
#include <math.h>

#define N 64
#define F 64
#define W 40
#define D 512
#define LSM 9.0f
#define LLSE 6.0f
#define MARG 0.2f
#define EPSV 1e-8f
#define DK 128
#define PAD 133  // row stride (floats) for staged chunks: conflict-free scalar reads

// ---------------- kernel 1: n1[i*F+f] = ||images[i,f,:]|| ----------------
__global__ void k_n1(const float* __restrict__ img, float* __restrict__ n1) {
  int i = blockIdx.x;
  int t = threadIdx.x;           // 256 threads: 4 per row
  int f = t >> 2, q = t & 3;
  const float4* p = (const float4*)(img + ((size_t)i * F + f) * D + q * 128);
  float s = 0.f;
#pragma unroll
  for (int k = 0; k < 32; ++k) {
    float4 v = p[k];
    s += v.x * v.x + v.y * v.y + v.z * v.z + v.w * v.w;
  }
  s += __shfl_xor(s, 1);
  s += __shfl_xor(s, 2);
  if (q == 0) n1[i * F + f] = sqrtf(s);
}

// ---------------- kernel 2: caption Gram G[j][w][w'] ----------------
__global__ void k_gram(const float* __restrict__ cap, float* __restrict__ G) {
  int j = blockIdx.x;
  const float* C = cap + (size_t)j * W * D;
  for (int e = threadIdx.x; e < W * W; e += blockDim.x) {
    int w = e / W, w2 = e % W;
    const float4* a = (const float4*)(C + w * D);
    const float4* b = (const float4*)(C + w2 * D);
    float s = 0.f;
#pragma unroll 8
    for (int k = 0; k < D / 4; ++k) {
      float4 x = a[k], y = b[k];
      s += x.x * y.x + x.y * y.y + x.z * y.z + x.w * y.w;
    }
    G[((size_t)j * W + w) * W + w2] = s;
  }
}

// ---------------- main fused kernel: one block per (i,j) pair ----------------
struct SmemP1 {
  float Cs[W][PAD];
  float Is[F][PAD];
};
struct SmemP23 {
  float Araw[W][F + 1];
  float rinv[W];
  float Gs[W][W + 1];
  float aw[F][W + 1];
  float red[8];
};
union Smem {
  SmemP1 p1;
  SmemP23 p23;
};

__global__ __launch_bounds__(256, 2) void k_main(
    const float* __restrict__ img, const float* __restrict__ cap,
    const int* __restrict__ imgL, const int* __restrict__ capL,
    const float* __restrict__ n1g, const float* __restrict__ Gg,
    float* __restrict__ S) {
  __shared__ Smem sm;
  int i = blockIdx.x, j = blockIdx.y;
  int t = threadIdx.x;
  int iL = imgL[i], cL = capL[j];

  // ---- phase 1: A[w][f] = cap[j,w,:]·img[i,f,:], K-chunked through LDS ----
  // thread t: fg = t&31 -> f0 = 2*fg (2 f's), wg = t>>5 -> w = wg+8k (5 w's)
  int fg = t & 31, wg = t >> 5;
  int f0 = fg * 2;
  float acc[5][2] = {{0.f}};

  for (int ch = 0; ch < D / DK; ++ch) {
    __syncthreads();  // prior chunk reads done before overwrite
    for (int idx = t; idx < W * (DK / 4); idx += 256) {
      int w = idx >> 5, d4 = idx & 31;
      float4 v = *(const float4*)(cap + ((size_t)(j * W + w)) * D + ch * DK + d4 * 4);
      sm.p1.Cs[w][d4 * 4 + 0] = v.x;
      sm.p1.Cs[w][d4 * 4 + 1] = v.y;
      sm.p1.Cs[w][d4 * 4 + 2] = v.z;
      sm.p1.Cs[w][d4 * 4 + 3] = v.w;
    }
    for (int idx = t; idx < F * (DK / 4); idx += 256) {
      int f = idx >> 5, d4 = idx & 31;
      float4 v = *(const float4*)(img + ((size_t)(i * F + f)) * D + ch * DK + d4 * 4);
      sm.p1.Is[f][d4 * 4 + 0] = v.x;
      sm.p1.Is[f][d4 * 4 + 1] = v.y;
      sm.p1.Is[f][d4 * 4 + 2] = v.z;
      sm.p1.Is[f][d4 * 4 + 3] = v.w;
    }
    __syncthreads();
#pragma unroll 4
    for (int d = 0; d < DK; ++d) {
      float iv0 = sm.p1.Is[f0][d];
      float iv1 = sm.p1.Is[f0 + 1][d];
#pragma unroll
      for (int k = 0; k < 5; ++k) {
        float cv = sm.p1.Cs[wg + 8 * k][d];
        acc[k][0] = fmaf(cv, iv0, acc[k][0]);
        acc[k][1] = fmaf(cv, iv1, acc[k][1]);
      }
    }
  }
  __syncthreads();  // phase-1 LDS reads done; p23 aliases p1

  // ---- phase 2: write masked raw A; load Gram; row norms ----
#pragma unroll
  for (int k = 0; k < 5; ++k) {
    int w = wg + 8 * k;
    bool wv = w < cL;
    sm.p23.Araw[w][f0] = (wv && f0 < iL) ? acc[k][0] : 0.f;
    sm.p23.Araw[w][f0 + 1] = (wv && (f0 + 1) < iL) ? acc[k][1] : 0.f;
  }
  for (int idx = t; idx < W * W; idx += 256) {
    sm.p23.Gs[idx / W][idx % W] = Gg[(size_t)j * W * W + idx];
  }
  __syncthreads();
  if (t < W) {
    float s = 0.f;
    for (int f = 0; f < F; ++f) {
      float a = sm.p23.Araw[t][f];
      float l = a > 0.f ? a : 0.1f * a;
      s = fmaf(l, l, s);
    }
    sm.p23.rinv[t] = 1.f / (sqrtf(s) + EPSV);
  }
  __syncthreads();

  // ---- phase 3: per-frame softmax over words + Gram-based n2 + LSE ----
  // remap: c = t&3 (word-chunk), f = t>>2
  int c = t & 3, f = t >> 2;
  float ar[10], lg[10], ew[10];
  float m = -1e30f;
#pragma unroll
  for (int k = 0; k < 10; ++k) {
    int w = c + 4 * k;
    float a = sm.p23.Araw[w][f];
    float l = a > 0.f ? a : 0.1f * a;
    float logit = LSM * l * sm.p23.rinv[w];
    ar[k] = a;
    lg[k] = (w < cL) ? logit : -1e30f;
    m = fmaxf(m, lg[k]);
  }
  m = fmaxf(m, __shfl_xor(m, 1));
  m = fmaxf(m, __shfl_xor(m, 2));
  float se = 0.f, sn = 0.f;
#pragma unroll
  for (int k = 0; k < 10; ++k) {
    int w = c + 4 * k;
    float e = (w < cL) ? __expf(lg[k] - m) : 0.f;
    ew[k] = e;
    se += e;
    sn = fmaf(e, ar[k], sn);
  }
  se += __shfl_xor(se, 1);
  se += __shfl_xor(se, 2);
  sn += __shfl_xor(sn, 1);
  sn += __shfl_xor(sn, 2);
  float inv = 1.f / se;
#pragma unroll
  for (int k = 0; k < 10; ++k) {
    int w = c + 4 * k;
    sm.p23.aw[f][w] = ew[k] * inv;
  }
  __syncthreads();
  float np = 0.f;
#pragma unroll
  for (int k = 0; k < 10; ++k) {
    int w = c + 4 * k;
    if (w < cL) {
      float awk = ew[k] * inv;
      float ts = 0.f;
#pragma unroll 8
      for (int w2 = 0; w2 < W; ++w2)
        ts = fmaf(sm.p23.Gs[w][w2], sm.p23.aw[f][w2], ts);
      np = fmaf(awk, ts, np);
    }
  }
  np += __shfl_xor(np, 1);
  np += __shfl_xor(np, 2);

  float num = sn * inv;
  float n2 = sqrtf(np);
  float n1v = n1g[i * F + f];
  float sim = num / fmaxf(n1v * n2, EPSV);
  float ef = (f < iL) ? __expf(LLSE * sim) : 0.f;

  // reduce ef over f (each f replicated on 4 lanes -> keep c==0 only)
  float v = (c == 0) ? ef : 0.f;
#pragma unroll
  for (int off = 1; off < 64; off <<= 1) v += __shfl_xor(v, off);
  int wid = t >> 6;
  if ((t & 63) == 0) sm.p23.red[wid] = v;
  __syncthreads();
  if (t == 0) {
    float tot = sm.p23.red[0] + sm.p23.red[1] + sm.p23.red[2] + sm.p23.red[3];
    S[j * N + i] = __logf(tot) / LLSE;
  }
}

// ---------------- kernel 4: contrastive loss reduction ----------------
__global__ void k_loss(const float* __restrict__ S, float* __restrict__ out) {
  __shared__ float red[128];
  int t = threadIdx.x;  // 128 threads: t<64 rows (cost_s), t>=64 cols (cost_im)
  float m = -1e30f;
  if (t < 64) {
    int a = t;
    float da = S[a * N + a];
    for (int b = 0; b < N; ++b)
      if (b != a) m = fmaxf(m, MARG + S[a * N + b] - da);
  } else {
    int b = t - 64;
    float db = S[b * N + b];
    for (int a = 0; a < N; ++a)
      if (a != b) m = fmaxf(m, MARG + S[a * N + b] - db);
  }
  m = fmaxf(m, 0.f);
  red[t] = m;
  __syncthreads();
  if (t == 0) {
    float s = 0.f;
    for (int k = 0; k < 128; ++k) s += red[k];
    *out = s;
  }
}

extern "C" void kernel_launch(void* const* d_in, const int* in_sizes, int n_in,
                              void* d_out, int out_size, void* d_ws, size_t ws_size,
                              hipStream_t stream) {
  const float* img = (const float*)d_in[0];
  const float* cap = (const float*)d_in[1];
  const int* imgL = (const int*)d_in[2];
  const int* capL = (const int*)d_in[3];

  float* n1 = (float*)d_ws;            // N*F floats
  float* G = n1 + N * F;               // N*W*W floats
  float* S = G + N * W * W;            // N*N floats

  k_n1<<<N, 256, 0, stream>>>(img, n1);
  k_gram<<<N, 256, 0, stream>>>(cap, G);
  dim3 grid(N, N);
  k_main<<<grid, 256, 0, stream>>>(img, cap, imgL, capL, n1, G, S);
  k_loss<<<1, 128, 0, stream>>>(S, (float*)d_out);
}

// Round 2
// 158.223 us; speedup vs baseline: 3.3313x; 3.3313x over previous
//
#include <hip/hip_runtime.h>
#include <math.h>

#define N 64
#define F 64
#define W 40
#define D 512
#define LSM 9.0f
#define LLSE 6.0f
#define MARG 0.2f
#define STRA 68   // Araw row stride in floats (bank-friendly, 16B-aligned rows)

typedef _Float16 f16x8 __attribute__((ext_vector_type(8)));
typedef float f32x4 __attribute__((ext_vector_type(4)));

__device__ inline void gll16(const void* g, void* l) {
  __builtin_amdgcn_global_load_lds(
      (const __attribute__((address_space(1))) unsigned int*)g,
      (__attribute__((address_space(3))) unsigned int*)l, 16, 0, 0);
}

// ---------------- n1[i*F+f] = ||images[i,f,:]|| (fp32) ----------------
__global__ void k_n1(const float* __restrict__ img, float* __restrict__ n1) {
  int i = blockIdx.x;
  int t = threadIdx.x;  // 256 threads: 4 per row
  int f = t >> 2, q = t & 3;
  const float4* p = (const float4*)(img + ((size_t)i * F + f) * D + q * 128);
  float s = 0.f;
#pragma unroll
  for (int k = 0; k < 32; ++k) {
    float4 v = p[k];
    s += v.x * v.x + v.y * v.y + v.z * v.z + v.w * v.w;
  }
  s += __shfl_xor(s, 1);
  s += __shfl_xor(s, 2);
  if (q == 0) n1[i * F + f] = sqrtf(s);
}

// ---- fp16 convert + swizzle images -> [i][ch][f][128], halfidx ^= (f&7)<<3 ----
__global__ void k_cvt_img(const float* __restrict__ img, _Float16* __restrict__ dst) {
  int b = blockIdx.x;        // 256 blocks
  int i = b >> 2, fq = b & 3;
  for (int idx = threadIdx.x; idx < 16 * 512; idx += 256) {
    int f = fq * 16 + (idx >> 9);
    int d = idx & 511;
    float v = img[((size_t)i * F + f) * D + d];
    int ch = d >> 7, din = d & 127;
    dst[(size_t)i * 32768 + ch * 8192 + f * 128 + (din ^ ((f & 7) << 3))] = (_Float16)v;
  }
}

// ---- fp16 convert + swizzle captions -> [j][ch][w48][128] (rows 40..47 zero) ----
__global__ void k_cvt_cap(const float* __restrict__ cap, _Float16* __restrict__ dst) {
  int b = blockIdx.x;        // 256 blocks
  int j = b >> 2, wq = b & 3;
  for (int idx = threadIdx.x; idx < 12 * 512; idx += 256) {
    int w = wq * 12 + (idx >> 9);
    int d = idx & 511;
    float v = (w < W) ? cap[((size_t)j * W + w) * D + d] : 0.f;
    int ch = d >> 7, din = d & 127;
    dst[(size_t)j * 24576 + ch * 6144 + w * 128 + (din ^ ((w & 7) << 3))] = (_Float16)v;
  }
}

// ---- Gram fp16: G_h[j][w48][64], entry (w,k) = cap_w . cap_k, swizzled ----
__global__ void k_gram_h(const float* __restrict__ cap, _Float16* __restrict__ G) {
  int b = blockIdx.x;        // 256 blocks
  int j = b >> 2, kq = b & 3;
  for (int idx = threadIdx.x; idx < 48 * 16; idx += 256) {
    int w = idx >> 4;
    int k = kq * 16 + (idx & 15);
    float s = 0.f;
    if (w < W && k < W) {
      const float4* a = (const float4*)(cap + ((size_t)j * W + w) * D);
      const float4* c = (const float4*)(cap + ((size_t)j * W + k) * D);
#pragma unroll 8
      for (int q = 0; q < D / 4; ++q) {
        float4 x = a[q], y = c[q];
        s += x.x * y.x + x.y * y.y + x.z * y.z + x.w * y.w;
      }
    }
    G[(size_t)j * 3072 + w * 64 + (k ^ ((w & 7) << 3))] = (_Float16)s;
  }
}

// ---------------- main fused kernel: one block per (i,j) pair ----------------
__global__ __launch_bounds__(256, 2) void k_main(
    const _Float16* __restrict__ img_h, const _Float16* __restrict__ cap_h,
    const int* __restrict__ imgL, const int* __restrict__ capL,
    const float* __restrict__ n1g, const _Float16* __restrict__ G_h,
    float* __restrict__ S) {
  __shared__ __align__(16) _Float16 capS[48 * 128];  // 12 KB
  __shared__ __align__(16) _Float16 imgS[64 * 128];  // 16 KB
  __shared__ __align__(16) _Float16 Gs[48 * 64];     // 6 KB
  __shared__ __align__(16) _Float16 Es[64 * 64];     // 8 KB
  __shared__ __align__(16) float Araw[40 * STRA];    // 10.9 KB
  __shared__ float rinv[40];
  __shared__ float numu[64];
  __shared__ float red[4];

  int t = threadIdx.x;
  int lane = t & 63, wv = t >> 6;
  int i = blockIdx.x, j = blockIdx.y;
  int iL = imgL[i], cL = capL[j];

  // issue Gram staging early (6 KB = 6 x 1KB instrs)
  {
    const char* gb = (const char*)(G_h + (size_t)j * 3072);
    for (int n = wv; n < 6; n += 4)
      gll16(gb + n * 1024 + lane * 16, (char*)Gs + n * 1024);
  }

  // ---- phase 1: A[w][f] via fp16 MFMA, K chunked 4x128 ----
  const char* capb = (const char*)(cap_h + (size_t)j * 24576);
  const char* imgb = (const char*)(img_h + (size_t)i * 32768);
  int koff = (lane >> 4) * 8;
  int rlo = lane & 15;
  f32x4 acc[3];
#pragma unroll
  for (int mt = 0; mt < 3; ++mt) acc[mt] = (f32x4)0.f;

  for (int ch = 0; ch < 4; ++ch) {
    __syncthreads();  // prior chunk consumed
    for (int n = wv; n < 12; n += 4)
      gll16(capb + ch * 12288 + n * 1024 + lane * 16, (char*)capS + n * 1024);
    for (int n = wv; n < 16; n += 4)
      gll16(imgb + ch * 16384 + n * 1024 + lane * 16, (char*)imgS + n * 1024);
    __syncthreads();  // drains vmcnt -> data ready
    int fr = wv * 16 + rlo;
    int fsw = (fr & 7) << 3;
#pragma unroll
    for (int k0 = 0; k0 < 128; k0 += 32) {
      int kk = k0 + koff;
      f16x8 bfrag = *(const f16x8*)&imgS[fr * 128 + (kk ^ fsw)];
#pragma unroll
      for (int mt = 0; mt < 3; ++mt) {
        int wr = mt * 16 + rlo;
        f16x8 afrag = *(const f16x8*)&capS[wr * 128 + (kk ^ ((wr & 7) << 3))];
        acc[mt] = __builtin_amdgcn_mfma_f32_16x16x32_f16(afrag, bfrag, acc[mt], 0, 0, 0);
      }
    }
  }

  // ---- write masked Araw[w][f] ----
  int fcol = wv * 16 + rlo;
#pragma unroll
  for (int mt = 0; mt < 3; ++mt) {
#pragma unroll
    for (int r = 0; r < 4; ++r) {
      int wr = mt * 16 + (lane >> 4) * 4 + r;
      if (wr < W) {
        float v = acc[mt][r];
        Araw[wr * STRA + fcol] = (wr < cL && fcol < iL) ? v : 0.f;
      }
    }
  }
  __syncthreads();

  // ---- rnorm over f per w (leaky then l2) ----
  if (t < 160) {
    int w = t >> 2, q = t & 3;
    const float4* p = (const float4*)&Araw[w * STRA + q * 16];
    float s = 0.f;
#pragma unroll
    for (int k = 0; k < 4; ++k) {
      float4 v = p[k];
      float a0 = v.x > 0.f ? v.x : 0.1f * v.x;
      float a1 = v.y > 0.f ? v.y : 0.1f * v.y;
      float a2 = v.z > 0.f ? v.z : 0.1f * v.z;
      float a3 = v.w > 0.f ? v.w : 0.1f * v.w;
      s += a0 * a0 + a1 * a1 + a2 * a2 + a3 * a3;
    }
    s += __shfl_xor(s, 1);
    s += __shfl_xor(s, 2);
    if (q == 0) rinv[w] = 1.f / (sqrtf(s) + 1e-8f);
  }
  __syncthreads();

  // ---- softmax (unnormalized e) + num_u, write E fp16 swizzled ----
  {
    int c = t & 3, f = t >> 2;
    int esw = (f & 7) << 3;
    float ar[10], lgk[10];
    float m = -1e30f;
#pragma unroll
    for (int k = 0; k < 10; ++k) {
      int w = c + 4 * k;
      float a = Araw[w * STRA + f];
      float l = a > 0.f ? a : 0.1f * a;
      float lg = LSM * l * rinv[w];
      ar[k] = a;
      lgk[k] = (w < cL) ? lg : -1e30f;
      m = fmaxf(m, lgk[k]);
    }
    m = fmaxf(m, __shfl_xor(m, 1));
    m = fmaxf(m, __shfl_xor(m, 2));
    float sn = 0.f;
#pragma unroll
    for (int k = 0; k < 10; ++k) {
      int w = c + 4 * k;
      float e = (w < cL) ? __expf(lgk[k] - m) : 0.f;
      Es[f * 64 + (w ^ esw)] = (_Float16)e;
      sn = fmaf(e, ar[k], sn);
    }
    sn += __shfl_xor(sn, 1);
    sn += __shfl_xor(sn, 2);
    if (c == 0) numu[f] = sn;
  }
  // zero-pad E columns w=40..63
  for (int idx = t; idx < 24 * 64; idx += 256) {
    int f2 = idx & 63, w2 = 40 + (idx >> 6);
    Es[f2 * 64 + (w2 ^ ((f2 & 7) << 3))] = (_Float16)0.f;
  }
  __syncthreads();

  // ---- P = E * G via MFMA (K=64 incl zero pad); n2u^2 = sum_w P.E ----
  {
    int rowf = wv * 16 + rlo;
    int asw = (rowf & 7) << 3;
    f32x4 P[3];
#pragma unroll
    for (int nt = 0; nt < 3; ++nt) P[nt] = (f32x4)0.f;
#pragma unroll
    for (int k0 = 0; k0 < 64; k0 += 32) {
      int kk = k0 + koff;
      f16x8 ea = *(const f16x8*)&Es[rowf * 64 + (kk ^ asw)];
#pragma unroll
      for (int nt = 0; nt < 3; ++nt) {
        int wr = nt * 16 + rlo;
        f16x8 gb = *(const f16x8*)&Gs[wr * 64 + (kk ^ ((wr & 7) << 3))];
        P[nt] = __builtin_amdgcn_mfma_f32_16x16x32_f16(ea, gb, P[nt], 0, 0, 0);
      }
    }
    float n2p[4] = {0.f, 0.f, 0.f, 0.f};
#pragma unroll
    for (int nt = 0; nt < 3; ++nt) {
      int wcol = nt * 16 + rlo;
#pragma unroll
      for (int r = 0; r < 4; ++r) {
        int fr2 = wv * 16 + (lane >> 4) * 4 + r;
        float ev = (float)Es[fr2 * 64 + (wcol ^ ((fr2 & 7) << 3))];
        n2p[r] = fmaf(P[nt][r], ev, n2p[r]);
      }
    }
#pragma unroll
    for (int d2 = 1; d2 < 16; d2 <<= 1) {
#pragma unroll
      for (int r = 0; r < 4; ++r) n2p[r] += __shfl_xor(n2p[r], d2);
    }
    int r = lane & 3;
    float n2sq = n2p[0];
    if (r == 1) n2sq = n2p[1];
    if (r == 2) n2sq = n2p[2];
    if (r == 3) n2sq = n2p[3];
    int fmy = wv * 16 + (lane >> 4) * 4 + r;
    float nm = numu[fmy];
    float n1v = n1g[i * F + fmy];
    float denom = n1v * sqrtf(fmaxf(n2sq, 0.f));
    float sim = nm / fmaxf(denom, 1e-20f);
    float ef = (fmy < iL) ? __expf(LLSE * sim) : 0.f;
    float val = ((lane & 12) == 0) ? ef : 0.f;
#pragma unroll
    for (int d2 = 1; d2 < 64; d2 <<= 1) val += __shfl_xor(val, d2);
    if (lane == 0) red[wv] = val;
  }
  __syncthreads();
  if (t == 0) S[j * N + i] = __logf(red[0] + red[1] + red[2] + red[3]) * (1.f / LLSE);
}

// ---------------- contrastive loss reduction ----------------
__global__ void k_loss(const float* __restrict__ S, float* __restrict__ out) {
  __shared__ float red[128];
  int t = threadIdx.x;  // t<64 rows (cost_s), t>=64 cols (cost_im)
  float m = -1e30f;
  if (t < 64) {
    int a = t;
    float da = S[a * N + a];
    for (int b = 0; b < N; ++b)
      if (b != a) m = fmaxf(m, MARG + S[a * N + b] - da);
  } else {
    int b = t - 64;
    float db = S[b * N + b];
    for (int a = 0; a < N; ++a)
      if (a != b) m = fmaxf(m, MARG + S[a * N + b] - db);
  }
  m = fmaxf(m, 0.f);
  red[t] = m;
  __syncthreads();
  if (t == 0) {
    float s = 0.f;
    for (int k = 0; k < 128; ++k) s += red[k];
    *out = s;
  }
}

extern "C" void kernel_launch(void* const* d_in, const int* in_sizes, int n_in,
                              void* d_out, int out_size, void* d_ws, size_t ws_size,
                              hipStream_t stream) {
  const float* img = (const float*)d_in[0];
  const float* cap = (const float*)d_in[1];
  const int* imgL = (const int*)d_in[2];
  const int* capL = (const int*)d_in[3];

  char* wsb = (char*)d_ws;
  float* n1 = (float*)wsb;                                    // 16 KB
  float* S = (float*)(wsb + 16384);                           // 16 KB
  _Float16* img_h = (_Float16*)(wsb + 32768);                 // 4 MB
  _Float16* cap_h = (_Float16*)(wsb + 32768 + 4194304);       // 3 MB
  _Float16* G_h = (_Float16*)(wsb + 32768 + 4194304 + 3145728);  // 384 KB

  k_cvt_img<<<256, 256, 0, stream>>>(img, img_h);
  k_cvt_cap<<<256, 256, 0, stream>>>(cap, cap_h);
  k_n1<<<64, 256, 0, stream>>>(img, n1);
  k_gram_h<<<256, 256, 0, stream>>>(cap, G_h);
  dim3 grid(N, N);
  k_main<<<grid, 256, 0, stream>>>(img_h, cap_h, imgL, capL, n1, G_h, S);
  k_loss<<<1, 128, 0, stream>>>(S, (float*)d_out);
}

// Round 3
// 76.460 us; speedup vs baseline: 6.8937x; 2.0694x over previous
//
#include <hip/hip_runtime.h>
#include <math.h>

#define N 64
#define F 64
#define W 40
#define D 512
#define LSM 9.0f
#define LLSE 6.0f
#define MARG 0.2f
#define STRA 68  // Araw row stride (floats)

typedef _Float16 f16x8 __attribute__((ext_vector_type(8)));
typedef float f32x4 __attribute__((ext_vector_type(4)));

__device__ inline void gll16(const void* g, void* l) {
  __builtin_amdgcn_global_load_lds(
      (const __attribute__((address_space(1))) unsigned int*)g,
      (__attribute__((address_space(3))) unsigned int*)l, 16, 0, 0);
}

// sizes (halves): img_h per i = 64*512 = 32768 (linear [f][512])
//                 cap_h per j = 4*40*128 = 20480 ([ch][w][128], half-idx ^ ((w&7)<<3))
//                 G_h  per j = 48*64 = 3072 ([w][64], ^ ((w&7)<<3); zero outside 40x40)

// ---------------- fused preprocessing ----------------
// blocks [0,64): img convert (fp16 linear) + n1 row norms
// blocks [64,128): cap convert (fp16 swizzled, global+LDS) + Gram via MFMA
__global__ __launch_bounds__(256) void k_pre(
    const float* __restrict__ img, const float* __restrict__ cap,
    _Float16* __restrict__ img_h, _Float16* __restrict__ cap_h,
    _Float16* __restrict__ G_h, float* __restrict__ n1) {
  __shared__ __align__(16) _Float16 capT[4 * 48 * 128];  // 48 KB ([ch][48][128])
  int t = threadIdx.x;
  int lane = t & 63, wv = t >> 6;
  int b = blockIdx.x;
  if (b < N) {
    int i = b;
    const float* src = img + (size_t)i * F * D;
    _Float16* dst = img_h + (size_t)i * F * D;
#pragma unroll
    for (int k = 0; k < 16; ++k) {
      int off = (t + k * 256) * 8;
      float4 u = *(const float4*)(src + off);
      float4 v = *(const float4*)(src + off + 4);
      f16x8 h;
      h[0] = (_Float16)u.x; h[1] = (_Float16)u.y; h[2] = (_Float16)u.z; h[3] = (_Float16)u.w;
      h[4] = (_Float16)v.x; h[5] = (_Float16)v.y; h[6] = (_Float16)v.z; h[7] = (_Float16)v.w;
      *(f16x8*)(dst + off) = h;
    }
    int f = t >> 2, q = t & 3;
    const float4* p = (const float4*)(src + (size_t)f * D + q * 128);
    float s = 0.f;
#pragma unroll
    for (int k = 0; k < 32; ++k) {
      float4 v = p[k];
      s += v.x * v.x + v.y * v.y + v.z * v.z + v.w * v.w;
    }
    s += __shfl_xor(s, 1);
    s += __shfl_xor(s, 2);
    if (q == 0) n1[i * F + f] = sqrtf(s);
  } else {
    int j = b - N;
    const float* src = cap + (size_t)j * W * D;
    _Float16* dst = cap_h + (size_t)j * 20480;
#pragma unroll
    for (int k = 0; k < 10; ++k) {
      int idx = t + k * 256;  // 0..2559
      int w = idx >> 6, d = (idx & 63) * 8;
      int ch = d >> 7, din = d & 127;
      float4 u = *(const float4*)(src + (size_t)w * D + d);
      float4 v = *(const float4*)(src + (size_t)w * D + d + 4);
      f16x8 h;
      h[0] = (_Float16)u.x; h[1] = (_Float16)u.y; h[2] = (_Float16)u.z; h[3] = (_Float16)u.w;
      h[4] = (_Float16)v.x; h[5] = (_Float16)v.y; h[6] = (_Float16)v.z; h[7] = (_Float16)v.w;
      int pos = din ^ ((w & 7) << 3);
      *(f16x8*)(dst + ch * 5120 + w * 128 + pos) = h;
      *(f16x8*)(capT + ch * 6144 + w * 128 + pos) = h;
    }
    __syncthreads();
    // Gram = cap . cap^T via MFMA. Rows/cols >= 40 come from garbage LDS rows;
    // MFMA rows/cols are independent, and we zero them on store.
    int rlo = lane & 15, koff = (lane >> 4) * 8;
    int sw = (rlo & 7) << 3;
    _Float16* gb = G_h + (size_t)j * 3072;
    if (wv < 3) {
      f32x4 acc[3];
#pragma unroll
      for (int mt = 0; mt < 3; ++mt) acc[mt] = (f32x4)0.f;
      int cb = wv * 16 + rlo;  // B row (= output col block)
#pragma unroll
      for (int ks = 0; ks < 16; ++ks) {
        int kk = ks * 32 + koff;
        int ch = kk >> 7, din = kk & 127;
        f16x8 bf = *(const f16x8*)(capT + ch * 6144 + cb * 128 + (din ^ sw));
#pragma unroll
        for (int mt = 0; mt < 3; ++mt) {
          int wr = mt * 16 + rlo;
          f16x8 af = *(const f16x8*)(capT + ch * 6144 + wr * 128 + (din ^ sw));
          acc[mt] = __builtin_amdgcn_mfma_f32_16x16x32_f16(af, bf, acc[mt], 0, 0, 0);
        }
      }
#pragma unroll
      for (int mt = 0; mt < 3; ++mt) {
#pragma unroll
        for (int r = 0; r < 4; ++r) {
          int w = mt * 16 + (lane >> 4) * 4 + r;
          int k = wv * 16 + rlo;
          float val = (w < W && k < W) ? acc[mt][r] : 0.f;
          gb[w * 64 + (k ^ ((w & 7) << 3))] = (_Float16)val;
        }
      }
    } else {
      // zero logical cols 48..63 (all 48 rows)
      for (int e = lane; e < 48 * 16; e += 64) {
        int w = e >> 4, k = 48 + (e & 15);
        gb[w * 64 + (k ^ ((w & 7) << 3))] = (_Float16)0.f;
      }
    }
  }
}

// ---------------- main fused kernel: one block per (i,j) pair ----------------
__global__ __launch_bounds__(256, 3) void k_main(
    const _Float16* __restrict__ img_h, const _Float16* __restrict__ cap_h,
    const int* __restrict__ imgL, const int* __restrict__ capL,
    const float* __restrict__ n1g, const _Float16* __restrict__ G_h,
    float* __restrict__ S) {
  __shared__ __align__(16) char buf[45056];         // capS (43K incl over-read) | {Araw, Es}
  __shared__ __align__(16) _Float16 Gs[48 * 64];    // 6 KB
  __shared__ float rinv[W];
  __shared__ float numu[F];
  __shared__ float red[4];

  _Float16* capS = (_Float16*)buf;                  // [ch][40][128] swizzled
  float* Araw = (float*)buf;                        // 40 x STRA floats (aliases capS)
  _Float16* Es = (_Float16*)(buf + 10880);          // 64 x 64 halves (aliases capS)

  int t = threadIdx.x;
  int lane = t & 63, wv = t >> 6;
  int i = blockIdx.x, j = blockIdx.y;
  int iL = imgL[i], cL = capL[j];
  int rlo = lane & 15, koff = (lane >> 4) * 8;
  int sw = (rlo & 7) << 3;

  // ---- stage capS (40 KB) + Gs (6 KB) via global_load_lds ----
  {
    const char* cb = (const char*)(cap_h + (size_t)j * 20480);
    for (int n2 = wv; n2 < 40; n2 += 4)
      gll16(cb + n2 * 1024 + lane * 16, buf + n2 * 1024);
    const char* gp = (const char*)(G_h + (size_t)j * 3072);
    for (int n2 = wv; n2 < 6; n2 += 4)
      gll16(gp + n2 * 1024 + lane * 16, (char*)Gs + n2 * 1024);
  }
  // ---- preload img B-fragments straight to registers (read exactly once) ----
  int fr = wv * 16 + rlo;
  const _Float16* ib = img_h + (size_t)i * 32768 + (size_t)fr * 512 + koff;
  f16x8 bfr[16];
#pragma unroll
  for (int m = 0; m < 16; ++m) bfr[m] = *(const f16x8*)(ib + m * 32);

  f32x4 acc[3];
#pragma unroll
  for (int mt = 0; mt < 3; ++mt) acc[mt] = (f32x4)0.f;

  __syncthreads();  // staging + preloads complete (barrier drains vmcnt)

  // ---- phase 1: A[w][f] = cap_w . img_f, single-barrier MFMA loop ----
#pragma unroll
  for (int ch = 0; ch < 4; ++ch) {
#pragma unroll
    for (int q = 0; q < 4; ++q) {
      int col = (q * 32 + koff) ^ sw;
      f16x8 bf = bfr[ch * 4 + q];
#pragma unroll
      for (int mt = 0; mt < 3; ++mt) {
        int wr = mt * 16 + rlo;
        f16x8 af = *(const f16x8*)(capS + ch * 5120 + wr * 128 + col);
        acc[mt] = __builtin_amdgcn_mfma_f32_16x16x32_f16(af, bf, acc[mt], 0, 0, 0);
      }
    }
  }
  __syncthreads();  // all capS reads done; Araw/Es may now overwrite

  // ---- write masked Araw[w][f] ----
#pragma unroll
  for (int mt = 0; mt < 3; ++mt) {
#pragma unroll
    for (int r = 0; r < 4; ++r) {
      int wr = mt * 16 + (lane >> 4) * 4 + r;
      if (wr < W) {
        float v = acc[mt][r];
        Araw[wr * STRA + fr] = (wr < cL && fr < iL) ? v : 0.f;
      }
    }
  }
  __syncthreads();

  // ---- rnorm over f per w (leaky then l2) ----
  if (t < 160) {
    int w = t >> 2, q = t & 3;
    const float4* p = (const float4*)&Araw[w * STRA + q * 16];
    float s = 0.f;
#pragma unroll
    for (int k = 0; k < 4; ++k) {
      float4 v = p[k];
      float a0 = v.x > 0.f ? v.x : 0.1f * v.x;
      float a1 = v.y > 0.f ? v.y : 0.1f * v.y;
      float a2 = v.z > 0.f ? v.z : 0.1f * v.z;
      float a3 = v.w > 0.f ? v.w : 0.1f * v.w;
      s += a0 * a0 + a1 * a1 + a2 * a2 + a3 * a3;
    }
    s += __shfl_xor(s, 1);
    s += __shfl_xor(s, 2);
    if (q == 0) rinv[w] = 1.f / (sqrtf(s) + 1e-8f);
  }
  __syncthreads();

  // ---- softmax (unnormalized e) + num_u, write E fp16 swizzled ----
  {
    int c = t & 3, f = t >> 2;
    int esw = (f & 7) << 3;
    float ar[10], lgk[10];
    float m = -1e30f;
#pragma unroll
    for (int k = 0; k < 10; ++k) {
      int w = c + 4 * k;
      float a = Araw[w * STRA + f];
      float l = a > 0.f ? a : 0.1f * a;
      float lg = LSM * l * rinv[w];
      ar[k] = a;
      lgk[k] = (w < cL) ? lg : -1e30f;
      m = fmaxf(m, lgk[k]);
    }
    m = fmaxf(m, __shfl_xor(m, 1));
    m = fmaxf(m, __shfl_xor(m, 2));
    float sn = 0.f;
#pragma unroll
    for (int k = 0; k < 10; ++k) {
      int w = c + 4 * k;
      float e = (w < cL) ? __expf(lgk[k] - m) : 0.f;
      Es[f * 64 + (w ^ esw)] = (_Float16)e;
      sn = fmaf(e, ar[k], sn);
    }
    sn += __shfl_xor(sn, 1);
    sn += __shfl_xor(sn, 2);
    if (c == 0) numu[f] = sn;
  }
  // zero-pad E columns w=40..63
  for (int idx = t; idx < 24 * 64; idx += 256) {
    int f2 = idx & 63, w2 = 40 + (idx >> 6);
    Es[f2 * 64 + (w2 ^ ((f2 & 7) << 3))] = (_Float16)0.f;
  }
  __syncthreads();

  // ---- P = E * G via MFMA; n2u^2 = sum_w' P . E ----
  {
    f32x4 P[3];
#pragma unroll
    for (int nt = 0; nt < 3; ++nt) P[nt] = (f32x4)0.f;
#pragma unroll
    for (int k0 = 0; k0 < 64; k0 += 32) {
      int kk = k0 + koff;
      f16x8 ea = *(const f16x8*)&Es[fr * 64 + (kk ^ sw)];
#pragma unroll
      for (int nt = 0; nt < 3; ++nt) {
        int wr = nt * 16 + rlo;
        f16x8 gbf = *(const f16x8*)&Gs[wr * 64 + (kk ^ sw)];
        P[nt] = __builtin_amdgcn_mfma_f32_16x16x32_f16(ea, gbf, P[nt], 0, 0, 0);
      }
    }
    float n2p[4] = {0.f, 0.f, 0.f, 0.f};
#pragma unroll
    for (int nt = 0; nt < 3; ++nt) {
      int wcol = nt * 16 + rlo;
#pragma unroll
      for (int r = 0; r < 4; ++r) {
        int fr2 = wv * 16 + (lane >> 4) * 4 + r;
        float ev = (float)Es[fr2 * 64 + (wcol ^ ((fr2 & 7) << 3))];
        n2p[r] = fmaf(P[nt][r], ev, n2p[r]);
      }
    }
#pragma unroll
    for (int d2 = 1; d2 < 16; d2 <<= 1) {
#pragma unroll
      for (int r = 0; r < 4; ++r) n2p[r] += __shfl_xor(n2p[r], d2);
    }
    int r = lane & 3;
    float n2sq = n2p[0];
    if (r == 1) n2sq = n2p[1];
    if (r == 2) n2sq = n2p[2];
    if (r == 3) n2sq = n2p[3];
    int fmy = wv * 16 + (lane >> 4) * 4 + r;
    float nm = numu[fmy];
    float n1v = n1g[i * F + fmy];
    float denom = n1v * sqrtf(fmaxf(n2sq, 0.f));
    float sim = nm / fmaxf(denom, 1e-20f);
    float ef = (fmy < iL) ? __expf(LLSE * sim) : 0.f;
    float val = ((lane & 12) == 0) ? ef : 0.f;
#pragma unroll
    for (int d2 = 1; d2 < 64; d2 <<= 1) val += __shfl_xor(val, d2);
    if (lane == 0) red[wv] = val;
  }
  __syncthreads();
  if (t == 0) S[j * N + i] = __logf(red[0] + red[1] + red[2] + red[3]) * (1.f / LLSE);
}

// ---------------- contrastive loss reduction ----------------
__global__ void k_loss(const float* __restrict__ S, float* __restrict__ out) {
  __shared__ float red[128];
  int t = threadIdx.x;
  float m = -1e30f;
  if (t < 64) {
    int a = t;
    float da = S[a * N + a];
    for (int b = 0; b < N; ++b)
      if (b != a) m = fmaxf(m, MARG + S[a * N + b] - da);
  } else {
    int b = t - 64;
    float db = S[b * N + b];
    for (int a = 0; a < N; ++a)
      if (a != b) m = fmaxf(m, MARG + S[a * N + b] - db);
  }
  m = fmaxf(m, 0.f);
  red[t] = m;
  __syncthreads();
  if (t == 0) {
    float s = 0.f;
    for (int k = 0; k < 128; ++k) s += red[k];
    *out = s;
  }
}

extern "C" void kernel_launch(void* const* d_in, const int* in_sizes, int n_in,
                              void* d_out, int out_size, void* d_ws, size_t ws_size,
                              hipStream_t stream) {
  const float* img = (const float*)d_in[0];
  const float* cap = (const float*)d_in[1];
  const int* imgL = (const int*)d_in[2];
  const int* capL = (const int*)d_in[3];

  char* wsb = (char*)d_ws;
  float* n1 = (float*)wsb;                               // 16 KB
  float* S = (float*)(wsb + 16384);                      // 16 KB
  _Float16* img_h = (_Float16*)(wsb + 32768);            // 4 MB
  _Float16* cap_h = (_Float16*)(wsb + 32768 + 4194304);  // 2.5 MB
  _Float16* G_h = (_Float16*)(wsb + 32768 + 4194304 + 2621440);  // 384 KB

  k_pre<<<128, 256, 0, stream>>>(img, cap, img_h, cap_h, G_h, n1);
  dim3 grid(N, N);
  k_main<<<grid, 256, 0, stream>>>(img_h, cap_h, imgL, capL, n1, G_h, S);
  k_loss<<<1, 128, 0, stream>>>(S, (float*)d_out);
}